// Round 11
// baseline (237.197 us; speedup 1.0000x reference)
//
#include <hip/hip_runtime.h>

// -------------------------------------------------------------------------
// GCN: h1 = relu(Agg(x@W1)+b1); h2 = relu(Agg(h1@W2)+b2); out = h2@Wl+bl
// R11 (corrected): overlap latency-bound preprocessing with MFMA-bound GEMM.
//   Dependency note: SCALE-GEMM needs dinv (from scan3), so layer-1 GEMM
//   cannot precede scan3. Instead it runs UNSCALED in fat1 (|| count), and
//   the dinv row-scaling moves to a fused rescale inside fat2 (|| place):
//   fat2's aux blocks also rescale t_bf rows by dinv (t is bf16; rescale =
//   load 8B, two mults, store 8B -- bandwidth-trivial 25.6MB round trip).
//   Chain: init -> fat1[gemm1(unscaled) || count] -> scan1+prepW23 ->
//          scan3 -> fat2[rescale || place] -> agg1 -> gemm2 -> agg2 -> cls.
//   R10's atomic-free place retained.
// -------------------------------------------------------------------------

typedef __attribute__((ext_vector_type(8))) __bf16 bf16x8;
typedef __attribute__((ext_vector_type(8))) short short8;
typedef __attribute__((ext_vector_type(4))) float f32x4;

__device__ inline float bf_lo(unsigned u) { return __uint_as_float(u << 16); }
__device__ inline float bf_hi(unsigned u) { return __uint_as_float(u & 0xffff0000u); }
__device__ inline unsigned short f2bf(float v) {
  return __builtin_bit_cast(unsigned short, (__bf16)v);
}

__device__ inline void prep_split(const float* __restrict__ W, int NN, int local,
                                  unsigned short* __restrict__ bh,
                                  unsigned short* __restrict__ bl_) {
  int nn = local >> 7, k = local & 127;
  float v = W[(size_t)k * NN + nn];
  __bf16 h = (__bf16)v;
  bh[local] = __builtin_bit_cast(unsigned short, h);
  bl_[local] = f2bf(v - (float)h);
}

// ---- init: zero cnt + split W1 ----
__global__ void k_init(int* __restrict__ cnt, int N,
                       const float* __restrict__ W1,
                       unsigned short* __restrict__ b1h, unsigned short* __restrict__ b1l) {
  int nbz = (N + 255) / 256;
  if ((int)blockIdx.x < nbz) {
    int i = blockIdx.x * 256 + threadIdx.x;
    if (i < N) cnt[i] = 0;
  } else {
    int idx = ((int)blockIdx.x - nbz) * 256 + threadIdx.x;
    if (idx < 16384) prep_split(W1, 128, idx, b1h, b1l);
  }
}

// ------------------- MFMA GEMM body (device fn) -------------------
template <int NT, bool A32, bool BIAS, bool OUT_BF16, bool SCALE>
__device__ void gemm_body(int bid,
    const void* __restrict__ Ahi_, const unsigned short* __restrict__ Alo,
    const unsigned short* __restrict__ Bhi, const unsigned short* __restrict__ Blo,
    const float* __restrict__ bias, const float* __restrict__ dinv,
    void* __restrict__ Cout, int M,
    unsigned short* __restrict__ lbh, unsigned short* __restrict__ lbl) {
  constexpr int K = 128;
  constexpr int NCOL = NT * 16;
  int t = threadIdx.x;
  int lane = t & 63, wave = t >> 6;
  int lm = lane & 15, lk = lane >> 4;
  int m_base = bid * 128 + wave * 32;
  const short8 zero8 = {0, 0, 0, 0, 0, 0, 0, 0};

  // ---- phase 1: prefetch all A fragments ----
  bf16x8 ah[2][4], al[2][4];
  if (A32) {
    const float* Af = (const float*)Ahi_;
    float4 ra[2][4][2];
#pragma unroll
    for (int mt = 0; mt < 2; ++mt) {
      int row = m_base + mt * 16 + lm;
#pragma unroll
      for (int ks = 0; ks < 4; ++ks) {
        if (row < M) {
          ra[mt][ks][0] = *(const float4*)&Af[(size_t)row * K + ks * 32 + lk * 8];
          ra[mt][ks][1] = *(const float4*)&Af[(size_t)row * K + ks * 32 + lk * 8 + 4];
        } else {
          ra[mt][ks][0] = make_float4(0.f, 0.f, 0.f, 0.f);
          ra[mt][ks][1] = make_float4(0.f, 0.f, 0.f, 0.f);
        }
      }
    }
#pragma unroll
    for (int mt = 0; mt < 2; ++mt)
#pragma unroll
      for (int ks = 0; ks < 4; ++ks) {
        float av[8] = {ra[mt][ks][0].x, ra[mt][ks][0].y, ra[mt][ks][0].z, ra[mt][ks][0].w,
                       ra[mt][ks][1].x, ra[mt][ks][1].y, ra[mt][ks][1].z, ra[mt][ks][1].w};
#pragma unroll
        for (int j = 0; j < 8; ++j) {
          __bf16 h = (__bf16)av[j];
          ah[mt][ks][j] = h;
          al[mt][ks][j] = (__bf16)(av[j] - (float)h);
        }
      }
  } else {
    const unsigned short* Ahi = (const unsigned short*)Ahi_;
#pragma unroll
    for (int mt = 0; mt < 2; ++mt) {
      int row = m_base + mt * 16 + lm;
#pragma unroll
      for (int ks = 0; ks < 4; ++ks) {
        if (row < M) {
          ah[mt][ks] = *(const bf16x8*)&Ahi[(size_t)row * K + ks * 32 + lk * 8];
          al[mt][ks] = *(const bf16x8*)&Alo[(size_t)row * K + ks * 32 + lk * 8];
        } else {
          ah[mt][ks] = __builtin_bit_cast(bf16x8, zero8);
          al[mt][ks] = __builtin_bit_cast(bf16x8, zero8);
        }
      }
    }
  }

  // ---- phase 2: cooperative B staging (XOR-swizzled 16B chunks) ----
  for (int c = t; c < NCOL * 16; c += 256) {
    int r = c >> 4, q = c & 15;
    int sq = q ^ (r & 15);
    *(short8*)&lbh[r * K + sq * 8] = *(const short8*)&Bhi[r * K + q * 8];
    *(short8*)&lbl[r * K + sq * 8] = *(const short8*)&Blo[r * K + q * 8];
  }
  __syncthreads();

  // ---- phase 3: pure LDS + MFMA ----
  f32x4 acc[2][NT] = {};
#pragma unroll
  for (int ks = 0; ks < 4; ++ks) {
    int chunk = ks * 4 + lk;
    bf16x8 bh[NT], bl[NT];
#pragma unroll
    for (int nt = 0; nt < NT; ++nt) {
      int r = nt * 16 + lm;
      int sq = chunk ^ lm;
      bh[nt] = *(const bf16x8*)&lbh[r * K + sq * 8];
      bl[nt] = *(const bf16x8*)&lbl[r * K + sq * 8];
    }
#pragma unroll
    for (int mt = 0; mt < 2; ++mt)
#pragma unroll
      for (int nt = 0; nt < NT; ++nt) {
        acc[mt][nt] = __builtin_amdgcn_mfma_f32_16x16x32_bf16(ah[mt][ks], bh[nt], acc[mt][nt], 0, 0, 0);
        acc[mt][nt] = __builtin_amdgcn_mfma_f32_16x16x32_bf16(ah[mt][ks], bl[nt], acc[mt][nt], 0, 0, 0);
        acc[mt][nt] = __builtin_amdgcn_mfma_f32_16x16x32_bf16(al[mt][ks], bh[nt], acc[mt][nt], 0, 0, 0);
      }
  }

  // ---- epilogue ----
#pragma unroll
  for (int mt = 0; mt < 2; ++mt) {
#pragma unroll
    for (int r = 0; r < 4; ++r) {
      int row = m_base + mt * 16 + lk * 4 + r;
      if (row < M) {
        float dr = SCALE ? dinv[row] : 1.f;
#pragma unroll
        for (int nt = 0; nt < NT; ++nt) {
          int col = nt * 16 + lm;
          float v = acc[mt][nt][r];
          if (SCALE) v *= dr;
          if (BIAS) v += bias[col];
          if (OUT_BF16)
            ((unsigned short*)Cout)[(size_t)row * NCOL + col] = f2bf(v);
          else
            __builtin_nontemporal_store(v, &((float*)Cout)[(size_t)row * NCOL + col]);
        }
      }
    }
  }
}

#define AUX_BLOCKS 512

// ---- fat1: gemm1 UNSCALED (blocks [0,G)) || count+rank ----
__global__ __launch_bounds__(256) void k_fat1(
    const float* __restrict__ x,
    const unsigned short* __restrict__ b1h, const unsigned short* __restrict__ b1l,
    unsigned short* __restrict__ t_bf, int M, int G,
    const int* __restrict__ dst, int E, int* __restrict__ cnt, int* __restrict__ rank) {
  __shared__ alignas(16) unsigned short lbh[128 * 128];
  __shared__ alignas(16) unsigned short lbl[128 * 128];
  int b = blockIdx.x;
  if (b < G) {
    gemm_body<8, true, false, true, false>(b, x, nullptr, b1h, b1l,
                                           nullptr, nullptr, t_bf, M, lbh, lbl);
  } else {
    for (int i = (b - G) * 256 + threadIdx.x; i < E; i += AUX_BLOCKS * 256)
      rank[i] = atomicAdd(&cnt[dst[i]], 1);
  }
}

// ---- fat2: rescale t_bf rows by dinv + write zero row (blocks [0,RB)) || place ----
__global__ __launch_bounds__(256) void k_fat2(
    unsigned short* __restrict__ t_bf, const float* __restrict__ dinv, int N, int RB,
    const int* __restrict__ src, const int* __restrict__ dst,
    const int* __restrict__ rank, const int* __restrict__ row_off, int E,
    int* __restrict__ edges) {
  int b = blockIdx.x;
  if (b < RB) {
    // 64 threads per row-quarter: each thread handles 8B (4 bf16) of a row.
    // block covers 8 rows: thread t -> row = b*8 + t/32, seg = t%32.
    int row = b * 8 + (threadIdx.x >> 5);
    int seg = threadIdx.x & 31;
    if (row < N) {
      float d = dinv[row];
      uint2 u = *(uint2*)&t_bf[(size_t)row * 128 + seg * 4];
      ushort4 o;
      o.x = f2bf(d * bf_lo(u.x));
      o.y = f2bf(d * bf_hi(u.x));
      o.z = f2bf(d * bf_lo(u.y));
      o.w = f2bf(d * bf_hi(u.y));
      *(ushort4*)&t_bf[(size_t)row * 128 + seg * 4] = o;
    } else if (row == N) {  // zero row for agg OOB lanes
      *(uint2*)&t_bf[(size_t)N * 128 + seg * 4] = make_uint2(0u, 0u);
    }
  } else {
    for (int e = (b - RB) * 256 + threadIdx.x; e < E; e += AUX_BLOCKS * 256) {
      int d = dst[e];
      int pos = row_off[d] + rank[e];
      __builtin_nontemporal_store(src[e], &edges[pos]);
    }
  }
}

// ---- standalone GEMM wrapper ----
template <int NT, bool A32, bool BIAS, bool OUT_BF16, bool SCALE>
__global__ __launch_bounds__(256) void gemm3(
    const void* __restrict__ Ahi_, const unsigned short* __restrict__ Alo,
    const unsigned short* __restrict__ Bhi, const unsigned short* __restrict__ Blo,
    const float* __restrict__ bias, const float* __restrict__ dinv,
    void* __restrict__ Cout, int M) {
  __shared__ alignas(16) unsigned short lbh[NT * 16 * 128];
  __shared__ alignas(16) unsigned short lbl[NT * 16 * 128];
  gemm_body<NT, A32, BIAS, OUT_BF16, SCALE>(blockIdx.x, Ahi_, Alo, Bhi, Blo,
                                            bias, dinv, Cout, M, lbh, lbl);
}

// second SCALE-gemm (layer 2) must also write the zero row: wrapper variant
template <int NT>
__global__ __launch_bounds__(256) void gemm3_scale_zrow(
    const unsigned short* __restrict__ Ahi, const unsigned short* __restrict__ Alo,
    const unsigned short* __restrict__ Bhi, const unsigned short* __restrict__ Blo,
    const float* __restrict__ dinv, unsigned short* __restrict__ Cout, int M) {
  __shared__ alignas(16) unsigned short lbh[NT * 16 * 128];
  __shared__ alignas(16) unsigned short lbl[NT * 16 * 128];
  if (blockIdx.x == 0 && threadIdx.x < 64) {  // zero row M
    *(unsigned*)&Cout[(size_t)M * NT * 16 + threadIdx.x * 2] = 0u;
  }
  gemm_body<NT, false, false, true, true>(blockIdx.x, Ahi, Alo, Bhi, Blo,
                                          nullptr, dinv, Cout, M, lbh, lbl);
}

// fat kernel: blocks [0, nb) scan1 partials; [nb, ...) prep W2 + Wl
__global__ void k_scan1_prepW(const int* __restrict__ cnt, int n, int* __restrict__ partial,
                              int nb,
                              const float* __restrict__ W2, const float* __restrict__ Wl,
                              unsigned short* __restrict__ b2h, unsigned short* __restrict__ b2l,
                              unsigned short* __restrict__ blh, unsigned short* __restrict__ bll) {
  if ((int)blockIdx.x < nb) {
    __shared__ int s[256];
    int i = blockIdx.x * 256 + threadIdx.x;
    s[threadIdx.x] = (i < n) ? cnt[i] : 0;
    __syncthreads();
    for (int off = 128; off > 0; off >>= 1) {
      if (threadIdx.x < off) s[threadIdx.x] += s[threadIdx.x + off];
      __syncthreads();
    }
    if (threadIdx.x == 0) partial[blockIdx.x] = s[0];
  } else {
    int idx = ((int)blockIdx.x - nb) * 256 + threadIdx.x;
    if (idx < 16384)      prep_split(W2, 128, idx, b2h, b2l);
    else if (idx < 24576) prep_split(Wl, 64, idx - 16384, blh, bll);
  }
}

// scan3: block base from partials + exclusive scan -> row_off, dinv
__global__ void k_scan3(const int* __restrict__ cnt, const int* __restrict__ partial,
                        int nb, int n, int* __restrict__ row_off,
                        float* __restrict__ dinv) {
  __shared__ int s[256];
  __shared__ int base_s;
  int t = threadIdx.x;
  s[t] = (t < nb && t < (int)blockIdx.x) ? partial[t] : 0;
  __syncthreads();
  for (int off = 128; off > 0; off >>= 1) {
    if (t < off) s[t] += s[t + off];
    __syncthreads();
  }
  if (t == 0) base_s = s[0];
  __syncthreads();
  int base = base_s;
  __syncthreads();

  int i = blockIdx.x * 256 + t;
  int v = (i < n) ? cnt[i] : 0;
  s[t] = v;
  __syncthreads();
  for (int off = 1; off < 256; off <<= 1) {
    int u = (t >= off) ? s[t - off] : 0;
    __syncthreads();
    s[t] += u;
    __syncthreads();
  }
  int incl = s[t];
  int excl = incl - v;
  if (i < n) {
    row_off[i] = base + excl;
    dinv[i] = rsqrtf((float)(v + 1));
    if (i == n - 1) row_off[n] = base + incl;
  }
}

// ------------------- aggregation: 4 edges x 16 lanes x 16B, 4B edges -------------------
__global__ __launch_bounds__(256) void k_agg(const unsigned short* __restrict__ t,
                      const int* __restrict__ row_off,
                      const int* __restrict__ edges,
                      const float* __restrict__ dinv, const float* __restrict__ bias,
                      unsigned short* __restrict__ ghi, unsigned short* __restrict__ glo,
                      int n) {
  int wave = threadIdx.x >> 6;
  int lane = threadIdx.x & 63;
  int g = lane >> 4;
  int fl = lane & 15;          // features fl*8 .. fl*8+7
  int node = blockIdx.x * 4 + wave;
  if (node >= n) return;
  int2 ro = *(const int2*)&row_off[node];
  int e0 = ro.x, e1 = ro.y;
  int last = e1 - 1;

  float acc[8] = {};
  for (int base = e0; base < e1; base += 8) {
    int i0 = base + g, i1 = base + 4 + g;
    int s0 = edges[i0 < e1 ? i0 : last];
    int s1 = edges[i1 < e1 ? i1 : last];
    s0 = i0 < e1 ? s0 : n;     // zero row
    s1 = i1 < e1 ? s1 : n;
    uint4 u0 = *(const uint4*)&t[(size_t)s0 * 128 + fl * 8];
    uint4 u1 = *(const uint4*)&t[(size_t)s1 * 128 + fl * 8];
    acc[0] += bf_lo(u0.x) + bf_lo(u1.x);
    acc[1] += bf_hi(u0.x) + bf_hi(u1.x);
    acc[2] += bf_lo(u0.y) + bf_lo(u1.y);
    acc[3] += bf_hi(u0.y) + bf_hi(u1.y);
    acc[4] += bf_lo(u0.z) + bf_lo(u1.z);
    acc[5] += bf_hi(u0.z) + bf_hi(u1.z);
    acc[6] += bf_lo(u0.w) + bf_lo(u1.w);
    acc[7] += bf_hi(u0.w) + bf_hi(u1.w);
  }
#pragma unroll
  for (int j = 0; j < 8; ++j) {
    acc[j] += __shfl_xor(acc[j], 16);
    acc[j] += __shfl_xor(acc[j], 32);
  }
  if (g == 0) {
    float di = dinv[node];
    uint4 sv = *(const uint4*)&t[(size_t)node * 128 + fl * 8];
    acc[0] += bf_lo(sv.x); acc[1] += bf_hi(sv.x);
    acc[2] += bf_lo(sv.y); acc[3] += bf_hi(sv.y);
    acc[4] += bf_lo(sv.z); acc[5] += bf_hi(sv.z);
    acc[6] += bf_lo(sv.w); acc[7] += bf_hi(sv.w);
    float4 bb0 = *(const float4*)&bias[fl * 8];
    float4 bb1 = *(const float4*)&bias[fl * 8 + 4];
    float bb[8] = {bb0.x, bb0.y, bb0.z, bb0.w, bb1.x, bb1.y, bb1.z, bb1.w};
    short8 ho, lo_;
#pragma unroll
    for (int j = 0; j < 8; ++j) {
      float s = fmaxf(acc[j] * di + bb[j], 0.f);
      __bf16 h = (__bf16)s;
      ho[j] = __builtin_bit_cast(short, h);
      lo_[j] = (short)f2bf(s - (float)h);
    }
    *(short8*)&ghi[(size_t)node * 128 + fl * 8] = ho;
    *(short8*)&glo[(size_t)node * 128 + fl * 8] = lo_;
  }
}

extern "C" void kernel_launch(void* const* d_in, const int* in_sizes, int n_in,
                              void* d_out, int out_size, void* d_ws, size_t ws_size,
                              hipStream_t stream) {
  const float* x  = (const float*)d_in[0];
  const int*   ei = (const int*)d_in[1];
  const float* W1 = (const float*)d_in[2];
  const float* b1 = (const float*)d_in[3];
  const float* W2 = (const float*)d_in[4];
  const float* b2 = (const float*)d_in[5];
  const float* Wl = (const float*)d_in[6];
  const float* bl = (const float*)d_in[7];
  float* out = (float*)d_out;

  const int D = 128;
  int N = in_sizes[0] / D;
  int E = in_sizes[1] / 2;
  const int* src = ei;
  const int* dst = ei + E;

  uintptr_t ws = (uintptr_t)d_ws;
  auto take = [&](size_t bytes) {
    uintptr_t p = ws;
    ws += (bytes + 15) & ~(size_t)15;
    return p;
  };
  unsigned short* t_bf = (unsigned short*)take(((size_t)N + 1) * D * 2);  // + zero row
  unsigned short* xh   = (unsigned short*)take((size_t)N * D * 2);
  unsigned short* xl   = (unsigned short*)take((size_t)N * D * 2);
  int*   edges   = (int*)take((size_t)E * 4);
  int*   rank    = (int*)take((size_t)E * 4);
  int*   cnt     = (int*)take((size_t)N * sizeof(int));
  int*   row_off = (int*)take(((size_t)N + 1) * sizeof(int));
  float* dinv    = (float*)take((size_t)N * sizeof(float));
  int*   partial = (int*)take(256 * sizeof(int));
  unsigned short* b1h = (unsigned short*)take(128 * 128 * 2);
  unsigned short* b1l = (unsigned short*)take(128 * 128 * 2);
  unsigned short* b2h = (unsigned short*)take(128 * 128 * 2);
  unsigned short* b2l = (unsigned short*)take(128 * 128 * 2);
  unsigned short* blh = (unsigned short*)take(128 * 64 * 2);
  unsigned short* bll = (unsigned short*)take(128 * 64 * 2);

  int nb_n = (N + 255) / 256;            // 196 (fits single-block base reduce)
  int gemm_blocks = (N + 127) / 128;     // 391
  int agg_blocks = (N + 3) / 4;
  int rescale_blocks = (N + 8) / 8;      // covers rows 0..N (incl zero row N)

  // 1) init: zero cnt + split W1
  k_init<<<nb_n + 64, 256, 0, stream>>>(cnt, N, W1, b1h, b1l);
  // 2) fat1: full layer-1 GEMM (unscaled) || count(+rank)
  k_fat1<<<gemm_blocks + AUX_BLOCKS, 256, 0, stream>>>(x, b1h, b1l, t_bf, N,
                                                       gemm_blocks, dst, E, cnt, rank);
  // 3) scan1 partials || split W2, Wl
  k_scan1_prepW<<<nb_n + 96, 256, 0, stream>>>(cnt, N, partial, nb_n,
                                               W2, Wl, b2h, b2l, blh, bll);
  // 4) scan3 -> row_off, dinv
  k_scan3<<<nb_n, 256, 0, stream>>>(cnt, partial, nb_n, N, row_off, dinv);
  // 5) fat2: rescale t_bf by dinv (+ zero row) || place
  k_fat2<<<rescale_blocks + AUX_BLOCKS, 256, 0, stream>>>(t_bf, dinv, N, rescale_blocks,
                                                          src, dst, rank, row_off, E, edges);
  // 6) layer-1 aggregation
  k_agg<<<agg_blocks, 256, 0, stream>>>(t_bf, row_off, edges, dinv, b1, xh, xl, N);
  // 7) layer-2 GEMM (scaled, writes zero row)
  gemm3_scale_zrow<8><<<gemm_blocks, 256, 0, stream>>>(xh, xl, b2h, b2l, dinv, t_bf, N);
  // 8) layer-2 aggregation
  k_agg<<<agg_blocks, 256, 0, stream>>>(t_bf, row_off, edges, dinv, b2, xh, xl, N);
  // 9) classifier
  gemm3<4, false, true, false, false><<<gemm_blocks, 256, 0, stream>>>(
      xh, xl, blh, bll, bl, nullptr, out, N);
}